// Round 1
// baseline (2087.942 us; speedup 1.0000x reference)
//
#include <hip/hip_runtime.h>

#define NNODES 800000
#define CINC   32
#define COUTC  64
#define KT     27
#define EPSV   1e-5f

typedef _Float16 half8 __attribute__((ext_vector_type(8)));
typedef _Float16 half4 __attribute__((ext_vector_type(4)));
typedef float    f32x4 __attribute__((ext_vector_type(4)));

#define MFMA(A, B, C) __builtin_amdgcn_mfma_f32_16x16x32_f16((A), (B), (C), 0, 0, 0)

// ---------------------------------------------------------------------------
// GroupNorm over one lane-local group of 4 channels (matches jnp reference:
// mu = mean, var = mean((x-mu)^2), xn = (x-mu)*rsqrt(var+eps), then *w + b).
// ---------------------------------------------------------------------------
__device__ __forceinline__ f32x4 gn4(f32x4 v, const float* __restrict__ w,
                                     const float* __restrict__ b, int cb) {
  const float mu = (v[0] + v[1] + v[2] + v[3]) * 0.25f;
  f32x4 d;
#pragma unroll
  for (int j = 0; j < 4; ++j) d[j] = v[j] - mu;
  const float var = (d[0] * d[0] + d[1] * d[1] + d[2] * d[2] + d[3] * d[3]) * 0.25f;
  const float rs = 1.0f / sqrtf(var + EPSV);
  const f32x4 wv = *(const f32x4*)(w + cb);
  const f32x4 bv = *(const f32x4*)(b + cb);
  f32x4 r;
#pragma unroll
  for (int j = 0; j < 4; ++j) r[j] = d[j] * rs * wv[j] + bv[j];
  return r;
}

// ---------------------------------------------------------------------------
// Prepass 1: split f32 -> f16 hi + f16 lo (x = hi + lo up to ~2^-22 rel).
// ---------------------------------------------------------------------------
__global__ __launch_bounds__(256) void k_split(const float* __restrict__ x,
                                               _Float16* __restrict__ hi,
                                               _Float16* __restrict__ lo, int n4) {
  const int i = blockIdx.x * 256 + threadIdx.x;
  if (i >= n4) return;
  const f32x4 v = ((const f32x4*)x)[i];
  half4 h, l;
#pragma unroll
  for (int j = 0; j < 4; ++j) {
    h[j] = (_Float16)v[j];
    l[j] = (_Float16)(v[j] - (float)h[j]);
  }
  ((half4*)hi)[i] = h;
  ((half4*)lo)[i] = l;
}

// ---------------------------------------------------------------------------
// Prepass 2: pre-swizzle weights into the MFMA A-operand "LDS image" layout.
// waT: [27][tile t:4][h:2][lane:64][8 f16]  (per tap: 4096 f16 = 8 KB)
// wbT: [27][t:4][kc:2][h:2][lane:64][8 f16] (per tap: 8192 f16 = 16 KB)
// w1T: [t:4][h:2][lane:64][8 f16]
// lane l encodes: cout = 16*t + (l&15), cin chunk = (l>>4)*8 (+32*kc).
// A fragment read becomes a lane-contiguous 1024B region -> conflict-free
// ds_read_b128, and staging global->LDS is a straight linear copy.
// ---------------------------------------------------------------------------
__global__ __launch_bounds__(256) void k_prepw(const float* __restrict__ Wa,
                                               const float* __restrict__ Wb,
                                               const float* __restrict__ W1,
                                               _Float16* __restrict__ waT,
                                               _Float16* __restrict__ wbT,
                                               _Float16* __restrict__ w1T) {
  const int u = blockIdx.x * 256 + threadIdx.x;
  const float* s;
  _Float16* d;
  size_t db;
  int cin0, cout;
  if (u < 6912) {  // Wa: 27 taps * 4 tiles * 64 lanes
    const int tap = u >> 8, r = u & 255, t = r >> 6, l = r & 63;
    cin0 = (l >> 4) * 8;
    cout = t * 16 + (l & 15);
    s = Wa + (size_t)tap * CINC * COUTC;
    d = waT;
    db = ((size_t)(tap * 8 + t * 2) * 64 + l) * 8;
  } else if (u < 20736) {  // Wb: 27 * 4 * 2 kc * 64
    const int u2 = u - 6912;
    const int tap = u2 >> 9, r = u2 & 511, t = r >> 7, r2 = r & 127;
    const int kc = r2 >> 6, l = r2 & 63;
    cin0 = kc * 32 + (l >> 4) * 8;
    cout = t * 16 + (l & 15);
    s = Wb + (size_t)tap * COUTC * COUTC;
    d = wbT;
    db = ((size_t)(tap * 16 + t * 4 + kc * 2) * 64 + l) * 8;
  } else if (u < 20992) {  // W1: 4 * 64
    const int u3 = u - 20736, t = u3 >> 6, l = u3 & 63;
    cin0 = (l >> 4) * 8;
    cout = t * 16 + (l & 15);
    s = W1;
    d = w1T;
    db = ((size_t)(t * 2) * 64 + l) * 8;
  } else {
    return;
  }
  half8 h, l8;
#pragma unroll
  for (int j = 0; j < 8; ++j) {
    const float v = s[(size_t)(cin0 + j) * COUTC + cout];
    h[j] = (_Float16)v;
    l8[j] = (_Float16)(v - (float)h[j]);
  }
  *(half8*)(d + db) = h;          // hi plane
  *(half8*)(d + db + 512) = l8;   // lo plane (+64 lanes * 8)
}

// ---------------------------------------------------------------------------
// Kernel A: h = relu(GN(octree_conv(data, neigh, Wa))) -> f16 hi/lo
// block = 256 thr (4 waves), 128 nodes/block; wave = 32 nodes x 64 couts.
// Dt formulation: acc[t][nt] rows = couts (lane holds 4 consecutive = 1 GN
// group), cols = nodes. 3-term f16 split: hh + hl + lh per K-chunk.
// ---------------------------------------------------------------------------
__global__ __launch_bounds__(256, 3) void k_conva(
    const _Float16* __restrict__ dhi, const _Float16* __restrict__ dlo,
    const int* __restrict__ neigh, const _Float16* __restrict__ waT,
    const float* __restrict__ gw, const float* __restrict__ gb,
    _Float16* __restrict__ hhi, _Float16* __restrict__ hlo) {
  __shared__ int s_n[128 * KT];
  __shared__ _Float16 s_w[3 * 4096];  // 3 taps staged per chunk (24.6 KB)
  const int tid = threadIdx.x;
  const int wave = tid >> 6, lane = tid & 63;
  const int cl = lane & 15, q = lane >> 4;
  const int node0 = blockIdx.x * 128;

  for (int j = tid; j < 128 * KT; j += 256) s_n[j] = neigh[(size_t)node0 * KT + j];

  f32x4 acc[4][2] = {};
  const int ln0 = wave * 32 + cl;

  for (int c = 0; c < 9; ++c) {
    __syncthreads();
    {
      const f32x4* src = (const f32x4*)(waT + (size_t)c * 12288);
      f32x4* dst = (f32x4*)s_w;
#pragma unroll
      for (int i = 0; i < 6; ++i) dst[tid + i * 256] = src[tid + i * 256];
    }
    __syncthreads();
#pragma unroll
    for (int tl = 0; tl < 3; ++tl) {
      const int tap = c * 3 + tl;
      const int i0 = s_n[ln0 * KT + tap];
      const int i1 = s_n[(ln0 + 16) * KT + tap];
      const half8 xh0 = *(const half8*)(dhi + (size_t)i0 * 32 + q * 8);
      const half8 xl0 = *(const half8*)(dlo + (size_t)i0 * 32 + q * 8);
      const half8 xh1 = *(const half8*)(dhi + (size_t)i1 * 32 + q * 8);
      const half8 xl1 = *(const half8*)(dlo + (size_t)i1 * 32 + q * 8);
#pragma unroll
      for (int t = 0; t < 4; ++t) {
        const half8 wh = *(const half8*)(s_w + ((tl * 8 + t * 2) * 64 + lane) * 8);
        const half8 wl = *(const half8*)(s_w + ((tl * 8 + t * 2 + 1) * 64 + lane) * 8);
        acc[t][0] = MFMA(wh, xh0, acc[t][0]);
        acc[t][0] = MFMA(wh, xl0, acc[t][0]);
        acc[t][0] = MFMA(wl, xh0, acc[t][0]);
        acc[t][1] = MFMA(wh, xh1, acc[t][1]);
        acc[t][1] = MFMA(wh, xl1, acc[t][1]);
        acc[t][1] = MFMA(wl, xh1, acc[t][1]);
      }
    }
  }

#pragma unroll
  for (int t = 0; t < 4; ++t)
#pragma unroll
    for (int nt = 0; nt < 2; ++nt) {
      const int node = node0 + wave * 32 + nt * 16 + cl;
      const int cb = t * 16 + q * 4;
      const f32x4 g = gn4(acc[t][nt], gw, gb, cb);
      half4 h, l;
#pragma unroll
      for (int j = 0; j < 4; ++j) {
        const float v = fmaxf(g[j], 0.0f);
        h[j] = (_Float16)v;
        l[j] = (_Float16)(v - (float)h[j]);
      }
      *(half4*)(hhi + (size_t)node * 64 + cb) = h;
      *(half4*)(hlo + (size_t)node * 64 + cb) = l;
    }
}

// ---------------------------------------------------------------------------
// Kernel B: out = relu(GN(octree_conv(h, neigh, Wb)) + GN(data @ W1)) -> f32
// ---------------------------------------------------------------------------
__global__ __launch_bounds__(256, 3) void k_convb(
    const _Float16* __restrict__ hhi, const _Float16* __restrict__ hlo,
    const _Float16* __restrict__ dhi, const _Float16* __restrict__ dlo,
    const int* __restrict__ neigh, const _Float16* __restrict__ wbT,
    const _Float16* __restrict__ w1T,
    const float* __restrict__ gbw, const float* __restrict__ gbb,
    const float* __restrict__ gsw, const float* __restrict__ gsb,
    float* __restrict__ out) {
  __shared__ int s_n[128 * KT];
  __shared__ _Float16 s_w[2 * 8192];  // 2 taps staged per chunk (32 KB)
  const int tid = threadIdx.x;
  const int wave = tid >> 6, lane = tid & 63;
  const int cl = lane & 15, q = lane >> 4;
  const int node0 = blockIdx.x * 128;

  for (int j = tid; j < 128 * KT; j += 256) s_n[j] = neigh[(size_t)node0 * KT + j];

  f32x4 acc[4][2] = {};
  const int ln0 = wave * 32 + cl;

  for (int c = 0; c < 14; ++c) {
    const int tap0 = c * 2;
    const int ntaps = (tap0 + 2 <= KT) ? 2 : 1;
    __syncthreads();
    {
      const f32x4* src = (const f32x4*)(wbT + (size_t)tap0 * 8192);
      f32x4* dst = (f32x4*)s_w;
      for (int i = tid; i < ntaps * 1024; i += 256) dst[i] = src[i];
    }
    __syncthreads();
    for (int tl = 0; tl < ntaps; ++tl) {
      const int tap = tap0 + tl;
      const int i0 = s_n[ln0 * KT + tap];
      const int i1 = s_n[(ln0 + 16) * KT + tap];
      const _Float16* r0h = hhi + (size_t)i0 * 64 + q * 8;
      const _Float16* r0l = hlo + (size_t)i0 * 64 + q * 8;
      const _Float16* r1h = hhi + (size_t)i1 * 64 + q * 8;
      const _Float16* r1l = hlo + (size_t)i1 * 64 + q * 8;
      const half8 xh0a = *(const half8*)(r0h);
      const half8 xh0b = *(const half8*)(r0h + 32);
      const half8 xl0a = *(const half8*)(r0l);
      const half8 xl0b = *(const half8*)(r0l + 32);
      const half8 xh1a = *(const half8*)(r1h);
      const half8 xh1b = *(const half8*)(r1h + 32);
      const half8 xl1a = *(const half8*)(r1l);
      const half8 xl1b = *(const half8*)(r1l + 32);
#pragma unroll
      for (int t = 0; t < 4; ++t) {
        const int wb = (tl * 16 + t * 4) * 512;
        const half8 wha = *(const half8*)(s_w + wb + lane * 8);
        const half8 wla = *(const half8*)(s_w + wb + 512 + lane * 8);
        const half8 whb = *(const half8*)(s_w + wb + 1024 + lane * 8);
        const half8 wlb = *(const half8*)(s_w + wb + 1536 + lane * 8);
        acc[t][0] = MFMA(wha, xh0a, acc[t][0]);
        acc[t][0] = MFMA(wha, xl0a, acc[t][0]);
        acc[t][0] = MFMA(wla, xh0a, acc[t][0]);
        acc[t][0] = MFMA(whb, xh0b, acc[t][0]);
        acc[t][0] = MFMA(whb, xl0b, acc[t][0]);
        acc[t][0] = MFMA(wlb, xh0b, acc[t][0]);
        acc[t][1] = MFMA(wha, xh1a, acc[t][1]);
        acc[t][1] = MFMA(wha, xl1a, acc[t][1]);
        acc[t][1] = MFMA(wla, xh1a, acc[t][1]);
        acc[t][1] = MFMA(whb, xh1b, acc[t][1]);
        acc[t][1] = MFMA(whb, xl1b, acc[t][1]);
        acc[t][1] = MFMA(wlb, xh1b, acc[t][1]);
      }
    }
  }

  // Shortcut: sc = data @ W1 (K=32, identity "tap" on own node).
  f32x4 sc[4][2] = {};
  {
    const int n0g = node0 + wave * 32 + cl;
    const half8 sh0 = *(const half8*)(dhi + (size_t)n0g * 32 + q * 8);
    const half8 sl0 = *(const half8*)(dlo + (size_t)n0g * 32 + q * 8);
    const half8 sh1 = *(const half8*)(dhi + (size_t)(n0g + 16) * 32 + q * 8);
    const half8 sl1 = *(const half8*)(dlo + (size_t)(n0g + 16) * 32 + q * 8);
#pragma unroll
    for (int t = 0; t < 4; ++t) {
      const half8 wh = *(const half8*)(w1T + ((size_t)(t * 2) * 64 + lane) * 8);
      const half8 wl = *(const half8*)(w1T + ((size_t)(t * 2 + 1) * 64 + lane) * 8);
      sc[t][0] = MFMA(wh, sh0, sc[t][0]);
      sc[t][0] = MFMA(wh, sl0, sc[t][0]);
      sc[t][0] = MFMA(wl, sh0, sc[t][0]);
      sc[t][1] = MFMA(wh, sh1, sc[t][1]);
      sc[t][1] = MFMA(wh, sl1, sc[t][1]);
      sc[t][1] = MFMA(wl, sh1, sc[t][1]);
    }
  }

#pragma unroll
  for (int t = 0; t < 4; ++t)
#pragma unroll
    for (int nt = 0; nt < 2; ++nt) {
      const int node = node0 + wave * 32 + nt * 16 + cl;
      const int cb = t * 16 + q * 4;
      const f32x4 a = gn4(acc[t][nt], gbw, gbb, cb);
      const f32x4 s = gn4(sc[t][nt], gsw, gsb, cb);
      f32x4 o;
#pragma unroll
      for (int j = 0; j < 4; ++j) o[j] = fmaxf(a[j] + s[j], 0.0f);
      *(f32x4*)(out + (size_t)node * 64 + cb) = o;
    }
}

// ---------------------------------------------------------------------------
extern "C" void kernel_launch(void* const* d_in, const int* in_sizes, int n_in,
                              void* d_out, int out_size, void* d_ws, size_t ws_size,
                              hipStream_t stream) {
  const float* data = (const float*)d_in[0];
  const int* neigh = (const int*)d_in[1];
  const float* Wa = (const float*)d_in[2];
  const float* gaw = (const float*)d_in[3];
  const float* gab = (const float*)d_in[4];
  const float* Wb = (const float*)d_in[5];
  const float* gbw = (const float*)d_in[6];
  const float* gbb = (const float*)d_in[7];
  const float* W1 = (const float*)d_in[8];
  const float* gsw = (const float*)d_in[9];
  const float* gsb = (const float*)d_in[10];
  float* out = (float*)d_out;

  // Workspace layout (all 16B aligned), total ~307.9 MB:
  char* ws = (char*)d_ws;
  _Float16* dhi = (_Float16*)(ws);                    //  51,200,000 B
  _Float16* dlo = (_Float16*)(ws + 51200000);         //  51,200,000 B
  _Float16* hhi = (_Float16*)(ws + 102400000);        // 102,400,000 B
  _Float16* hlo = (_Float16*)(ws + 204800000);        // 102,400,000 B
  _Float16* waT = (_Float16*)(ws + 307200000);        //     221,184 B
  _Float16* wbT = (_Float16*)(ws + 307421184);        //     442,368 B
  _Float16* w1T = (_Float16*)(ws + 307863552);        //       8,192 B

  // Prepass
  k_split<<<25000, 256, 0, stream>>>(data, dhi, dlo, NNODES * CINC / 4);
  k_prepw<<<82, 256, 0, stream>>>(Wa, Wb, W1, waT, wbT, w1T);

  // conv3x3a + GN + ReLU -> h (f16 hi/lo)
  k_conva<<<NNODES / 128, 256, 0, stream>>>(dhi, dlo, neigh, waT, gaw, gab, hhi, hlo);

  // conv3x3b + GN, shortcut 1x1 + GN, add, ReLU -> out (f32)
  k_convb<<<NNODES / 128, 256, 0, stream>>>(hhi, hlo, dhi, dlo, neigh, wbT, w1T,
                                            gbw, gbb, gsw, gsb, out);
}